// Round 1
// baseline (16010.132 us; speedup 1.0000x reference)
//
#include <hip/hip_runtime.h>
#include <cstdint>

typedef long long ll;

// Problem constants
#define NB 8
#define NT 12
#define NF 64
#define NL 5
#define HH 64
#define WW 64
#define HWSZ 4096

// ---------------------------------------------------------------------------
// Downsample conv: x (B,12,128,128) -> seq (T,B,64,64,64), k=4 s=2 p=1, LeakyReLU
// block: 256 thr = 64 x * 4 rows; grid = B*768*16
__global__ __launch_bounds__(256) void k_down(
    const float* __restrict__ x, const float* __restrict__ Wd,
    const float* __restrict__ bd, float* __restrict__ seq) {
  int tid = threadIdx.x;
  int xo = tid & 63;
  int idx = blockIdx.x;
  int yo = ((idx & 15) << 2) | (tid >> 6);
  idx >>= 4;
  int oc = idx % 768;
  int b  = idx / 768;
  float acc = bd[oc];
  const float* wb = Wd + oc * 192;          // (12,4,4)
  const float* xb = x + (ll)b * (12 * 128 * 128);
  for (int ic = 0; ic < 12; ++ic) {
    const float* xi = xb + ic * (128 * 128);
    const float* wk = wb + ic * 16;
    #pragma unroll
    for (int ky = 0; ky < 4; ++ky) {
      int iy = 2 * yo - 1 + ky;
      if (iy < 0 || iy > 127) continue;
      #pragma unroll
      for (int kx = 0; kx < 4; ++kx) {
        int ix = 2 * xo - 1 + kx;
        if (ix < 0 || ix > 127) continue;
        acc += xi[iy * 128 + ix] * wk[ky * 4 + kx];
      }
    }
  }
  acc = acc >= 0.f ? acc : 0.2f * acc;
  int t = oc >> 6, f = oc & 63;
  seq[((((ll)t * NB + b) * NF + f) << 12) + (yo << 6) + xo] = acc;
}

// ---------------------------------------------------------------------------
// i2h conv 3x3 pad1: xin (B,64,64,64) -> out (B,192,64,64)
// each block computes 3 channels (cog, cog+64, cog+128) sharing input reads.
// grid = B*64*16, block 256
__global__ __launch_bounds__(256) void k_i2h(
    const float* __restrict__ xin, const float* __restrict__ Wc,
    const float* __restrict__ bc, float* __restrict__ outp) {
  int tid = threadIdx.x;
  int xo = tid & 63;
  int idx = blockIdx.x;
  int yo = ((idx & 15) << 2) | (tid >> 6);
  idx >>= 4;
  int cog = idx & 63;
  int b   = idx >> 6;
  float a0 = bc[cog], a1 = bc[cog + 64], a2 = bc[cog + 128];
  for (int ci = 0; ci < 64; ++ci) {
    const float* ib = xin + (((ll)b * 64 + ci) << 12);
    const float* w0 = Wc + ((cog       ) * 64 + ci) * 9;
    const float* w1 = Wc + ((cog +  64) * 64 + ci) * 9;
    const float* w2 = Wc + ((cog + 128) * 64 + ci) * 9;
    #pragma unroll
    for (int ky = 0; ky < 3; ++ky) {
      int iy = yo - 1 + ky;
      if (iy < 0 || iy > 63) continue;
      #pragma unroll
      for (int kx = 0; kx < 3; ++kx) {
        int ix = xo - 1 + kx;
        if (ix < 0 || ix > 63) continue;
        float v = ib[(iy << 6) + ix];
        int wi = ky * 3 + kx;
        a0 += v * w0[wi];
        a1 += v * w1[wi];
        a2 += v * w2[wi];
      }
    }
  }
  ll ob = ((ll)b * 192) << 12;
  int po = (yo << 6) + xo;
  outp[ob + ((ll)(cog       ) << 12) + po] = a0;
  outp[ob + ((ll)(cog +  64) << 12) + po] = a1;
  outp[ob + ((ll)(cog + 128) << 12) + po] = a2;
}

// ---------------------------------------------------------------------------
// f1 = leaky( conv5(x_t, W_i2f) + conv5(hprev, W_h2f) ), out (B,32,64,64)
// hprev accessed as hprev + b*hsb + ci*HWSZ (strided view into d_out or zeros)
// grid = B*32*16, block 256
__global__ __launch_bounds__(256) void k_f1(
    const float* __restrict__ xin, const float* __restrict__ hprev, ll hsb,
    const float* __restrict__ Wi, const float* __restrict__ bi,
    const float* __restrict__ Wh, const float* __restrict__ bh,
    float* __restrict__ f1) {
  int tid = threadIdx.x;
  int xo = tid & 63;
  int idx = blockIdx.x;
  int yo = ((idx & 15) << 2) | (tid >> 6);
  idx >>= 4;
  int co = idx & 31;
  int b  = idx >> 5;
  float acc = bi[co] + bh[co];
  for (int ci = 0; ci < 64; ++ci) {
    const float* xb = xin + (((ll)b * 64 + ci) << 12);
    const float* hb = hprev + (ll)b * hsb + ((ll)ci << 12);
    const float* wi = Wi + (co * 64 + ci) * 25;
    const float* wh = Wh + (co * 64 + ci) * 25;
    #pragma unroll
    for (int ky = 0; ky < 5; ++ky) {
      int iy = yo - 2 + ky;
      if (iy < 0 || iy > 63) continue;
      #pragma unroll
      for (int kx = 0; kx < 5; ++kx) {
        int ix = xo - 2 + kx;
        if (ix < 0 || ix > 63) continue;
        int off = (iy << 6) + ix;
        int wk = ky * 5 + kx;
        acc += xb[off] * wi[wk] + hb[off] * wh[wk];
      }
    }
  }
  acc = acc >= 0.f ? acc : 0.2f * acc;
  f1[(((ll)b * 32 + co) << 12) + (yo << 6) + xo] = acc;
}

// ---------------------------------------------------------------------------
// flows = conv5(f1, W_flow), out (B,10,64,64). grid = B*10*16, block 256
__global__ __launch_bounds__(256) void k_flow(
    const float* __restrict__ f1, const float* __restrict__ Wf,
    const float* __restrict__ bf, float* __restrict__ flows) {
  int tid = threadIdx.x;
  int xo = tid & 63;
  int idx = blockIdx.x;
  int yo = ((idx & 15) << 2) | (tid >> 6);
  idx >>= 4;
  int co = idx % 10;
  int b  = idx / 10;
  float acc = bf[co];
  for (int ci = 0; ci < 32; ++ci) {
    const float* ib = f1 + (((ll)b * 32 + ci) << 12);
    const float* wk = Wf + (co * 32 + ci) * 25;
    #pragma unroll
    for (int ky = 0; ky < 5; ++ky) {
      int iy = yo - 2 + ky;
      if (iy < 0 || iy > 63) continue;
      #pragma unroll
      for (int kx = 0; kx < 5; ++kx) {
        int ix = xo - 2 + kx;
        if (ix < 0 || ix > 63) continue;
        acc += ib[(iy << 6) + ix] * wk[ky * 5 + kx];
      }
    }
  }
  flows[(((ll)b * 10 + co) << 12) + (yo << 6) + xo] = acc;
}

// ---------------------------------------------------------------------------
// warp: warped(b, l*64+c, y, x) = bilinear(hprev[b,c], x - fx, y - fy), zero pad
// grid = B*L*64 (b,l,y), block 256: x = tid&63, c = tid>>6 stepped by 4
__global__ __launch_bounds__(256) void k_warp(
    const float* __restrict__ flows, const float* __restrict__ hprev, ll hsb,
    float* __restrict__ warped) {
  int tid = threadIdx.x;
  int xo = tid & 63;
  int cg = tid >> 6;
  int idx = blockIdx.x;
  int yo = idx & 63;
  idx >>= 6;
  int l = idx % 5;
  int b = idx / 5;
  int po = (yo << 6) + xo;
  float fx = flows[(((ll)b * 10 + l * 2 + 0) << 12) + po];
  float fy = flows[(((ll)b * 10 + l * 2 + 1) << 12) + po];
  float px = (float)xo - fx;
  float py = (float)yo - fy;
  float x0f = floorf(px), y0f = floorf(py);
  int x0 = (int)x0f, y0 = (int)y0f;
  int x1 = x0 + 1, y1 = y0 + 1;
  float dx = px - x0f, dy = py - y0f;
  bool vx0 = (x0 >= 0) && (x0 <= 63);
  bool vx1 = (x1 >= 0) && (x1 <= 63);
  bool vy0 = (y0 >= 0) && (y0 <= 63);
  bool vy1 = (y1 >= 0) && (y1 <= 63);
  float wA = (vx0 && vy0) ? (1.f - dx) * (1.f - dy) : 0.f;  // (x0,y0)
  float wB = (vx0 && vy1) ? (1.f - dx) * dy         : 0.f;  // (x0,y1)
  float wC = (vx1 && vy0) ? dx * (1.f - dy)         : 0.f;  // (x1,y0)
  float wD = (vx1 && vy1) ? dx * dy                 : 0.f;  // (x1,y1)
  int cx0 = min(max(x0, 0), 63), cx1 = min(max(x1, 0), 63);
  int cy0 = min(max(y0, 0), 63), cy1 = min(max(y1, 0), 63);
  int o00 = (cy0 << 6) + cx0, o10 = (cy1 << 6) + cx0;
  int o01 = (cy0 << 6) + cx1, o11 = (cy1 << 6) + cx1;
  ll wbase = (((ll)b * 320 + (ll)l * 64) << 12) + po;
  for (int c = cg; c < 64; c += 4) {
    const float* hb = hprev + (ll)b * hsb + ((ll)c << 12);
    float v = wA * hb[o00] + wB * hb[o10] + wC * hb[o01] + wD * hb[o11];
    warped[wbase + ((ll)c << 12)] = v;
  }
}

// ---------------------------------------------------------------------------
// ret 1x1 conv over 320 channels + GRU gates, fused.
// block = (b, y): stage warped[*, y, :] column (320 ch x 64 px) in LDS in two
// chunks (48KB buffer), each wave computes 48 of 192 output channels with
// 12-way register blocking, then gates -> hnew written to d_out slab t.
// grid = B*64 = 512, block 256
__global__ __launch_bounds__(256) void k_retgate(
    const float* __restrict__ warped, const float* __restrict__ Wr,
    const float* __restrict__ br, const float* __restrict__ i2h,
    const float* __restrict__ hprev, ll hsb,
    float* __restrict__ outp, ll osb) {
  __shared__ float lds[192 * 64];
  int tid = threadIdx.x;
  int yo = blockIdx.x & 63;
  int b  = blockIdx.x >> 6;
  int px = tid & 63;
  int g  = __builtin_amdgcn_readfirstlane(tid >> 6);  // wave id 0..3

  float h2h[48];
  {
    const float* brp = br + g * 48;
    #pragma unroll
    for (int j = 0; j < 48; ++j) h2h[j] = brp[j];
  }

  const float* wbase = warped + (((ll)b * 320) << 12) + (yo << 6);

  // chunk A: ci 0..191
  for (int i = tid; i < 192 * 64; i += 256)
    lds[i] = wbase[((ll)(i >> 6) << 12) + (i & 63)];
  __syncthreads();
  #pragma unroll
  for (int jg = 0; jg < 4; ++jg) {
    const float* wr = Wr + (g * 48 + jg * 12) * 320;
    float a[12];
    #pragma unroll
    for (int k = 0; k < 12; ++k) a[k] = 0.f;
    for (int ci = 0; ci < 192; ++ci) {
      float v = lds[(ci << 6) + px];
      #pragma unroll
      for (int k = 0; k < 12; ++k) a[k] += wr[k * 320 + ci] * v;
    }
    #pragma unroll
    for (int k = 0; k < 12; ++k) h2h[jg * 12 + k] += a[k];
  }
  __syncthreads();

  // chunk B: ci 192..319
  for (int i = tid; i < 128 * 64; i += 256)
    lds[i] = wbase[((ll)((i >> 6) + 192) << 12) + (i & 63)];
  __syncthreads();
  #pragma unroll
  for (int jg = 0; jg < 4; ++jg) {
    const float* wr = Wr + (g * 48 + jg * 12) * 320 + 192;
    float a[12];
    #pragma unroll
    for (int k = 0; k < 12; ++k) a[k] = 0.f;
    for (int ci = 0; ci < 128; ++ci) {
      float v = lds[(ci << 6) + px];
      #pragma unroll
      for (int k = 0; k < 12; ++k) a[k] += wr[k * 320 + ci] * v;
    }
    #pragma unroll
    for (int k = 0; k < 12; ++k) h2h[jg * 12 + k] += a[k];
  }
  __syncthreads();

  // write h2h (192 x 64) into LDS
  #pragma unroll
  for (int j = 0; j < 48; ++j) lds[(g * 48 + j) * 64 + px] = h2h[j];
  __syncthreads();

  // gates
  const float* i2hb = i2h + (((ll)b * 192) << 12) + (yo << 6);
  const float* hpb  = hprev + (ll)b * hsb + (yo << 6);
  float* ob = outp + (ll)b * osb + (yo << 6);
  for (int i = tid; i < 64 * 64; i += 256) {
    int f  = i >> 6;
    int xx = i & 63;
    float ir = i2hb[((ll)(f      ) << 12) + xx];
    float iu = i2hb[((ll)(f +  64) << 12) + xx];
    float im = i2hb[((ll)(f + 128) << 12) + xx];
    float hr = lds[((f      ) << 6) + xx];
    float hu = lds[((f +  64) << 6) + xx];
    float hm = lds[((f + 128) << 6) + xx];
    float r = 1.f / (1.f + __expf(-(ir + hr)));
    float u = 1.f / (1.f + __expf(-(iu + hu)));
    float m = im + r * hm;
    m = m >= 0.f ? m : 0.2f * m;
    float hp = hpb[((ll)f << 12) + xx];
    ob[((ll)f << 12) + xx] = u * hp + (1.f - u) * m;
  }
}

// ---------------------------------------------------------------------------
extern "C" void kernel_launch(void* const* d_in, const int* in_sizes, int n_in,
                              void* d_out, int out_size, void* d_ws, size_t ws_size,
                              hipStream_t stream) {
  const float* x      = (const float*)d_in[0];
  const float* W_down = (const float*)d_in[1];
  const float* b_down = (const float*)d_in[2];
  const float* W_i2h  = (const float*)d_in[3];
  const float* b_i2h  = (const float*)d_in[4];
  const float* W_i2f  = (const float*)d_in[5];
  const float* b_i2f  = (const float*)d_in[6];
  const float* W_h2f  = (const float*)d_in[7];
  const float* b_h2f  = (const float*)d_in[8];
  const float* W_flow = (const float*)d_in[9];
  const float* b_flow = (const float*)d_in[10];
  const float* W_ret  = (const float*)d_in[11];
  const float* b_ret  = (const float*)d_in[12];
  float* out = (float*)d_out;

  // workspace layout (floats)
  const ll n_seq    = (ll)NT * NB * NF * HWSZ;   // 25,165,824
  const ll n_i2h    = (ll)NB * 192 * HWSZ;       //  6,291,456
  const ll n_f1     = (ll)NB * 32 * HWSZ;        //  1,048,576
  const ll n_flows  = (ll)NB * 10 * HWSZ;        //    327,680
  const ll n_warped = (ll)NB * 320 * HWSZ;       // 10,485,760
  const ll n_hzero  = (ll)NB * NF * HWSZ;        //  2,097,152
  const ll need = (n_seq + n_i2h + n_f1 + n_flows + n_warped + n_hzero) * 4;
  if ((ll)ws_size < need) return;

  float* seq    = (float*)d_ws;
  float* i2h_t  = seq + n_seq;
  float* f1b    = i2h_t + n_i2h;
  float* flowsb = f1b + n_f1;
  float* warpedb= flowsb + n_flows;
  float* hzero  = warpedb + n_warped;

  hipMemsetAsync(hzero, 0, (size_t)n_hzero * 4, stream);

  k_down<<<NB * 768 * 16, 256, 0, stream>>>(x, W_down, b_down, seq);

  const ll out_hsb = (ll)NT * NF * HWSZ;  // per-b stride in d_out
  for (int t = 0; t < NT; ++t) {
    const float* xt = seq + (ll)t * NB * NF * HWSZ;
    const float* hprev;
    ll hsb;
    if (t == 0) { hprev = hzero; hsb = (ll)NF * HWSZ; }
    else        { hprev = out + (ll)(t - 1) * NF * HWSZ; hsb = out_hsb; }

    k_i2h<<<NB * 64 * 16, 256, 0, stream>>>(xt, W_i2h, b_i2h, i2h_t);
    k_f1<<<NB * 32 * 16, 256, 0, stream>>>(xt, hprev, hsb, W_i2f, b_i2f,
                                           W_h2f, b_h2f, f1b);
    k_flow<<<NB * 10 * 16, 256, 0, stream>>>(f1b, W_flow, b_flow, flowsb);
    k_warp<<<NB * NL * 64, 256, 0, stream>>>(flowsb, hprev, hsb, warpedb);
    k_retgate<<<NB * 64, 256, 0, stream>>>(warpedb, W_ret, b_ret, i2h_t,
                                           hprev, hsb,
                                           out + (ll)t * NF * HWSZ, out_hsb);
  }
}

// Round 2
// 2532.536 us; speedup vs baseline: 6.3218x; 6.3218x over previous
//
#include <hip/hip_runtime.h>
#include <cstdint>

typedef long long ll;
typedef __bf16 bf16x8 __attribute__((ext_vector_type(8)));
typedef float f32x4 __attribute__((ext_vector_type(4)));
typedef unsigned int u32x4 __attribute__((ext_vector_type(4)));

#define NB 8
#define NT 12
#define NF 64
#define HWSZ 4096

struct alignas(8)  bh4 { __bf16 h[4]; };
struct alignas(16) bh8 { __bf16 h[8]; };

static __device__ inline f32x4 mfma16(bf16x8 a, bf16x8 b, f32x4 c) {
  return __builtin_amdgcn_mfma_f32_16x16x32_bf16(a, b, c, 0, 0, 0);
}
static __device__ inline bf16x8 ld8(const __bf16* p) {
  u32x4 u = *(const u32x4*)p;
  return __builtin_bit_cast(bf16x8, u);
}
static __device__ inline void st4(__bf16* p, float a0, float a1, float a2, float a3) {
  bh4 t; t.h[0] = (__bf16)a0; t.h[1] = (__bf16)a1; t.h[2] = (__bf16)a2; t.h[3] = (__bf16)a3;
  *(bh4*)p = t;
}

// Stage one spatial row (64 real px + halo) of a 64-channel NHWC bf16 map into
// LDS with G4 XOR swizzle (granule ^= xi&7). grow==nullptr -> zero row.
static __device__ void stage_row(__bf16* smrow, const __bf16* grow, int W, int HALO) {
  const int tid = threadIdx.x;
  u32x4 zz = {0u, 0u, 0u, 0u};
  if (grow == nullptr) {
    for (int i = tid; i < W * 8; i += 256)
      *(u32x4*)(smrow + i * 8) = zz;
  } else {
    #pragma unroll
    for (int it = 0; it < 2; ++it) {
      int i = tid + it * 256;
      int xr = i >> 3, g = i & 7;
      int xi = HALO + xr;
      u32x4 v = *(const u32x4*)(grow + xr * 64 + g * 8);
      *(u32x4*)(smrow + xi * 64 + ((g ^ (xi & 7)) * 8)) = v;
    }
    if (tid < HALO * 16) {
      int h = tid >> 3, g = tid & 7;
      int xi = (h < HALO) ? h : (W - 2 * HALO) + h;
      *(u32x4*)(smrow + xi * 64 + ((g ^ (xi & 7)) * 8)) = zz;
    }
  }
}

// ---------------------------------------------------------------------------
// Weight pre-transform (once per launch): bf16 [tap][oc][ci] layouts + fp32
// transposed down-weights. Grid-stride over 434688 elements.
__global__ __launch_bounds__(256) void k_prep(
    const float* __restrict__ Wd, const float* __restrict__ Wc,
    const float* __restrict__ Wi, const float* __restrict__ Wh,
    const float* __restrict__ Wfl, const float* __restrict__ Wret,
    float* __restrict__ Wd2, __bf16* __restrict__ Ai2h, __bf16* __restrict__ Af,
    __bf16* __restrict__ Afl, __bf16* __restrict__ Aret) {
  int n = blockIdx.x * 256 + threadIdx.x;
  if (n < 147456) {                       // Wd2[tap][oc] <- Wd[oc][tap]
    int tap = n / 768, oc = n % 768;
    Wd2[n] = Wd[oc * 192 + tap];
  } else if (n < 258048) {                // Ai2h[tap][o][c]
    int i = n - 147456;
    int tap = i / 12288, rem = i % 12288, o = rem / 64, c = rem % 64;
    Ai2h[i] = (__bf16)Wc[(o * 64 + c) * 9 + tap];
  } else if (n < 360448) {                // Af[src][tap][o][c]
    int i = n - 258048;
    int s = i / 51200, rem = i % 51200, tap = rem / 2048;
    int r2 = rem % 2048, o = r2 / 64, c = r2 % 64;
    const float* W = s ? Wh : Wi;
    Af[i] = (__bf16)W[(o * 64 + c) * 25 + tap];
  } else if (n < 373248) {                // Afl[tap][o(16 pad)][c]
    int i = n - 360448;
    int tap = i / 512, r2 = i % 512, o = r2 / 32, c = r2 % 32;
    Afl[i] = (__bf16)(o < 10 ? Wfl[(o * 32 + c) * 25 + tap] : 0.f);
  } else if (n < 434688) {                // Aret[o][c]
    int i = n - 373248;
    Aret[i] = (__bf16)Wret[i];
  }
}

// ---------------------------------------------------------------------------
// Downsample conv fp32: block = (b,y). Input tile in LDS once; 4 waves sweep
// 768 oc with wave-uniform SGPR weights. Output: seq bf16 NHWC [t][b][y][x][f].
__global__ __launch_bounds__(256) void k_down(
    const float* __restrict__ x, const float* __restrict__ Wd2,
    const float* __restrict__ bd, __bf16* __restrict__ seq) {
  __shared__ float sm[6240];              // [12 ic][4 ky][130 xi]
  int y = blockIdx.x & 63, b = blockIdx.x >> 6;
  int tid = threadIdx.x;
  for (int i = tid; i < 6240; i += 256) {
    int ic = i / 520, rem = i % 520, ky = rem / 130, xi = rem % 130;
    int ix = xi - 1, iy = 2 * y - 1 + ky;
    sm[i] = (ix >= 0 && ix < 128 && iy >= 0 && iy < 128)
                ? x[(((ll)(b * 12 + ic) * 128 + iy) << 7) + ix] : 0.f;
  }
  __syncthreads();
  int xl = tid & 63;
  int wv = __builtin_amdgcn_readfirstlane(tid >> 6);
  for (int og = 0; og < 24; ++og) {
    int oc0 = wv * 192 + og * 8;
    float acc[8];
    #pragma unroll
    for (int j = 0; j < 8; ++j) acc[j] = bd[oc0 + j];
    for (int ic = 0; ic < 12; ++ic) {
      #pragma unroll
      for (int ky = 0; ky < 4; ++ky) {
        int base = (ic * 4 + ky) * 130 + 2 * xl;
        float2 p0 = *(const float2*)(sm + base);
        float2 p1 = *(const float2*)(sm + base + 2);
        float v[4] = {p0.x, p0.y, p1.x, p1.y};
        const float* wp = Wd2 + (ll)(ic * 16 + ky * 4) * 768 + oc0;
        #pragma unroll
        for (int kx = 0; kx < 4; ++kx)
          #pragma unroll
          for (int j = 0; j < 8; ++j)
            acc[j] += v[kx] * wp[kx * 768 + j];
      }
    }
    int t = oc0 >> 6, f0 = oc0 & 63;
    bh8 o;
    #pragma unroll
    for (int j = 0; j < 8; ++j) {
      float a = acc[j];
      a = a >= 0.f ? a : 0.2f * a;
      o.h[j] = (__bf16)a;
    }
    *(bh8*)(seq + ((((ll)((t * NB + b) * 64 + y)) * 64 + xl) * 64) + f0) = o;
  }
}

// ---------------------------------------------------------------------------
// i2h 3x3 conv as MFMA implicit GEMM. block=(b,y): M=192, N=64px, K=9tapsx64.
// Wave w: M-tiles 3w..3w+2 x 4 N-tiles. Out fp32 NCHW (for gate epilogue).
__global__ __launch_bounds__(256) void k_i2h(
    const __bf16* __restrict__ xt, const __bf16* __restrict__ A,
    const float* __restrict__ bc, float* __restrict__ outp) {
  __shared__ __align__(16) __bf16 sm[3 * 66 * 64];
  int y = blockIdx.x & 63, b = blockIdx.x >> 6;
  int tid = threadIdx.x;
  int wv = __builtin_amdgcn_readfirstlane(tid >> 6);
  int lane = tid & 63, q = lane >> 4, lr = lane & 15;
  for (int ky = 0; ky < 3; ++ky) {
    int yr = y - 1 + ky;
    stage_row(sm + ky * 66 * 64,
              (yr >= 0 && yr < 64) ? xt + ((ll)(b * 64 + yr) << 12) : nullptr, 66, 1);
  }
  __syncthreads();
  f32x4 zv = {0.f, 0.f, 0.f, 0.f};
  f32x4 acc[3][4];
  #pragma unroll
  for (int mt = 0; mt < 3; ++mt)
    #pragma unroll
    for (int nt = 0; nt < 4; ++nt) acc[mt][nt] = zv;

  #pragma unroll
  for (int ky = 0; ky < 3; ++ky)
    #pragma unroll
    for (int kx = 0; kx < 3; ++kx) {
      int tap = ky * 3 + kx;
      #pragma unroll
      for (int ks = 0; ks < 2; ++ks) {
        bf16x8 bfr[4];
        #pragma unroll
        for (int nt = 0; nt < 4; ++nt) {
          int xi = nt * 16 + lr + kx;
          int gs = (ks * 4 + q) ^ (xi & 7);
          bfr[nt] = ld8(sm + (ky * 66 + xi) * 64 + gs * 8);
        }
        bf16x8 afr[3];
        #pragma unroll
        for (int mt = 0; mt < 3; ++mt)
          afr[mt] = ld8(A + ((ll)(tap * 192 + (wv * 3 + mt) * 16 + lr) * 64 + ks * 32 + q * 8));
        #pragma unroll
        for (int mt = 0; mt < 3; ++mt)
          #pragma unroll
          for (int nt = 0; nt < 4; ++nt)
            acc[mt][nt] = mfma16(afr[mt], bfr[nt], acc[mt][nt]);
      }
    }

  ll ob = ((ll)b * 192) << 12;
  #pragma unroll
  for (int mt = 0; mt < 3; ++mt)
    #pragma unroll
    for (int nt = 0; nt < 4; ++nt) {
      int px = nt * 16 + lr;
      #pragma unroll
      for (int r = 0; r < 4; ++r) {
        int oc = (wv * 3 + mt) * 16 + q * 4 + r;
        outp[ob + ((ll)oc << 12) + y * 64 + px] = acc[mt][nt][r] + bc[oc];
      }
    }
}

// ---------------------------------------------------------------------------
// f1 = leaky(i2f(x) + h2f(h)): M=32, K=25x64x2. Wave w: N-tile w, M-tiles 0,1.
// LDS reused sequentially for x then h tiles. Out bf16 NHWC [b][y][x][32].
static __device__ inline void f1_accum(const __bf16* sm, const __bf16* A,
                                       f32x4 acc[2], int wv, int q, int lr) {
  #pragma unroll
  for (int ky = 0; ky < 5; ++ky)
    #pragma unroll
    for (int kx = 0; kx < 5; ++kx) {
      int tap = ky * 5 + kx;
      int xi = wv * 16 + lr + kx;
      #pragma unroll
      for (int ks = 0; ks < 2; ++ks) {
        int gs = (ks * 4 + q) ^ (xi & 7);
        bf16x8 bfr = ld8(sm + (ky * 68 + xi) * 64 + gs * 8);
        #pragma unroll
        for (int mt = 0; mt < 2; ++mt) {
          bf16x8 afr = ld8(A + ((ll)(tap * 32 + mt * 16 + lr) * 64 + ks * 32 + q * 8));
          acc[mt] = mfma16(afr, bfr, acc[mt]);
        }
      }
    }
}

__global__ __launch_bounds__(256) void k_f1(
    const __bf16* __restrict__ xt, const __bf16* __restrict__ hb,
    const __bf16* __restrict__ Af, const float* __restrict__ bi,
    const float* __restrict__ bh, __bf16* __restrict__ f1buf) {
  __shared__ __align__(16) __bf16 sm[5 * 68 * 64];
  int y = blockIdx.x & 63, b = blockIdx.x >> 6;
  int tid = threadIdx.x;
  int wv = __builtin_amdgcn_readfirstlane(tid >> 6);
  int lane = tid & 63, q = lane >> 4, lr = lane & 15;
  f32x4 zv = {0.f, 0.f, 0.f, 0.f};
  f32x4 acc[2] = {zv, zv};

  for (int ky = 0; ky < 5; ++ky) {
    int yr = y - 2 + ky;
    stage_row(sm + ky * 68 * 64,
              (yr >= 0 && yr < 64) ? xt + ((ll)(b * 64 + yr) << 12) : nullptr, 68, 2);
  }
  __syncthreads();
  f1_accum(sm, Af, acc, wv, q, lr);
  __syncthreads();
  for (int ky = 0; ky < 5; ++ky) {
    int yr = y - 2 + ky;
    stage_row(sm + ky * 68 * 64,
              (yr >= 0 && yr < 64) ? hb + ((ll)(b * 64 + yr) << 12) : nullptr, 68, 2);
  }
  __syncthreads();
  f1_accum(sm, Af + 51200, acc, wv, q, lr);

  int px = wv * 16 + lr;
  __bf16* op = f1buf + ((ll)(b * 64 + y) * 64 + px) * 32;
  #pragma unroll
  for (int mt = 0; mt < 2; ++mt) {
    int oc0 = mt * 16 + q * 4;
    float v[4];
    #pragma unroll
    for (int r = 0; r < 4; ++r) {
      float a = acc[mt][r] + bi[oc0 + r] + bh[oc0 + r];
      v[r] = a >= 0.f ? a : 0.2f * a;
    }
    st4(op + oc0, v[0], v[1], v[2], v[3]);
  }
}

// ---------------------------------------------------------------------------
// flow conv 5x5: M=16 (10 used), K=25x32. B-frags straight from global f1buf
// NHWC with per-lane OOB masking. Out fp32 NCHW flows (B,10,64,64).
__global__ __launch_bounds__(256) void k_flow(
    const __bf16* __restrict__ f1buf, const __bf16* __restrict__ Afl,
    const float* __restrict__ bfl, float* __restrict__ flows) {
  int y = blockIdx.x & 63, b = blockIdx.x >> 6;
  int tid = threadIdx.x;
  int wv = __builtin_amdgcn_readfirstlane(tid >> 6);
  int lane = tid & 63, q = lane >> 4, lr = lane & 15;
  f32x4 acc = {0.f, 0.f, 0.f, 0.f};
  #pragma unroll
  for (int ky = 0; ky < 5; ++ky) {
    int yi = y + ky - 2;
    bool vy = (yi >= 0 && yi < 64);
    int yc = vy ? yi : 0;
    #pragma unroll
    for (int kx = 0; kx < 5; ++kx) {
      int tap = ky * 5 + kx;
      int xi = wv * 16 + lr + kx - 2;
      bool vx = (xi >= 0 && xi < 64);
      int xc = vx ? xi : 0;
      u32x4 raw = {0u, 0u, 0u, 0u};
      if (vy && vx)
        raw = *(const u32x4*)(f1buf + ((ll)(b * 64 + yc) * 64 + xc) * 32 + q * 8);
      bf16x8 bfr = __builtin_bit_cast(bf16x8, raw);
      bf16x8 afr = ld8(Afl + (ll)(tap * 16 + lr) * 32 + q * 8);
      acc = mfma16(afr, bfr, acc);
    }
  }
  #pragma unroll
  for (int r = 0; r < 4; ++r) {
    int oc = q * 4 + r;
    if (oc < 10)
      flows[((ll)(b * 10 + oc) << 12) + y * 64 + wv * 16 + lr] = acc[r] + bfl[oc];
  }
}

// ---------------------------------------------------------------------------
// warp: bilinear sample of hprev (bf16 NHWC, contiguous channels) at grid-flow.
// Out warped bf16 NHWC [b][y][x][320] (l-major channels).
__global__ __launch_bounds__(256) void k_warp(
    const float* __restrict__ flows, const __bf16* __restrict__ hb,
    __bf16* __restrict__ warped) {
  int y = blockIdx.x & 63, b = blockIdx.x >> 6;
  int tid = threadIdx.x;
  int x = tid & 63, cg = tid >> 6;
  const __bf16* hbb = hb + ((ll)b << 18);
  ll wrow = ((ll)(b * 64 + y) * 64 + x) * 320;
  #pragma unroll
  for (int l = 0; l < 5; ++l) {
    float fx = flows[((ll)(b * 10 + 2 * l) << 12) + y * 64 + x];
    float fy = flows[((ll)(b * 10 + 2 * l + 1) << 12) + y * 64 + x];
    float px = (float)x - fx, py = (float)y - fy;
    float x0f = floorf(px), y0f = floorf(py);
    int x0 = (int)x0f, y0 = (int)y0f, x1 = x0 + 1, y1 = y0 + 1;
    float dx = px - x0f, dy = py - y0f;
    bool vx0 = x0 >= 0 && x0 <= 63, vx1 = x1 >= 0 && x1 <= 63;
    bool vy0 = y0 >= 0 && y0 <= 63, vy1 = y1 >= 0 && y1 <= 63;
    float wA = (vx0 && vy0) ? (1.f - dx) * (1.f - dy) : 0.f;
    float wB = (vx0 && vy1) ? (1.f - dx) * dy : 0.f;
    float wC = (vx1 && vy0) ? dx * (1.f - dy) : 0.f;
    float wD = (vx1 && vy1) ? dx * dy : 0.f;
    int cx0 = min(max(x0, 0), 63), cx1 = min(max(x1, 0), 63);
    int cy0 = min(max(y0, 0), 63), cy1 = min(max(y1, 0), 63);
    int o00 = (cy0 * 64 + cx0) * 64, o10 = (cy1 * 64 + cx0) * 64;
    int o01 = (cy0 * 64 + cx1) * 64, o11 = (cy1 * 64 + cx1) * 64;
    #pragma unroll
    for (int it = 0; it < 2; ++it) {
      int c0 = (cg + it * 4) * 8;
      bf16x8 aA = ld8(hbb + o00 + c0), aB = ld8(hbb + o10 + c0);
      bf16x8 aC = ld8(hbb + o01 + c0), aD = ld8(hbb + o11 + c0);
      bh8 ov;
      #pragma unroll
      for (int i = 0; i < 8; ++i)
        ov.h[i] = (__bf16)(wA * (float)aA[i] + wB * (float)aB[i] +
                           wC * (float)aC[i] + wD * (float)aD[i]);
      *(bh8*)(warped + wrow + l * 64 + c0) = ov;
    }
  }
}

// ---------------------------------------------------------------------------
// ret 1x1 (M=192,K=320) MFMA + GRU gates fused. Wave w: N-tile w, 12 M-tiles.
// D layout makes (r,u,m) triplet per-lane: acc[ft], acc[ft+4], acc[ft+8].
__global__ __launch_bounds__(256) void k_retgate(
    const __bf16* __restrict__ warped, const __bf16* __restrict__ Aret,
    const float* __restrict__ br, const float* __restrict__ i2hb,
    const float* __restrict__ hprevf, ll hsb,
    float* __restrict__ outp, ll osb, __bf16* __restrict__ hbc) {
  int y = blockIdx.x & 63, b = blockIdx.x >> 6;
  int tid = threadIdx.x;
  int wv = __builtin_amdgcn_readfirstlane(tid >> 6);
  int lane = tid & 63, q = lane >> 4, lr = lane & 15;
  int px = wv * 16 + lr;
  const __bf16* bp = warped + ((ll)(b * 64 + y) * 64 + px) * 320;
  f32x4 zv = {0.f, 0.f, 0.f, 0.f};
  f32x4 acc[12];
  #pragma unroll
  for (int mt = 0; mt < 12; ++mt) acc[mt] = zv;
  for (int ks = 0; ks < 10; ++ks) {
    bf16x8 bfr = ld8(bp + ks * 32 + q * 8);
    #pragma unroll
    for (int mt = 0; mt < 12; ++mt) {
      bf16x8 afr = ld8(Aret + (ll)(mt * 16 + lr) * 320 + ks * 32 + q * 8);
      acc[mt] = mfma16(afr, bfr, acc[mt]);
    }
  }
  const float* ib = i2hb + (((ll)b * 192) << 12) + y * 64 + px;
  const float* hp = hprevf + (ll)b * hsb + y * 64 + px;
  float* ob = outp + (ll)b * osb + y * 64 + px;
  __bf16* hc = hbc + ((ll)(b * 64 + y) * 64 + px) * 64;
  #pragma unroll
  for (int ft = 0; ft < 4; ++ft) {
    float hn4[4];
    #pragma unroll
    for (int r = 0; r < 4; ++r) {
      int f = ft * 16 + q * 4 + r;
      float hr = acc[ft][r] + br[f];
      float hu = acc[ft + 4][r] + br[f + 64];
      float hm = acc[ft + 8][r] + br[f + 128];
      float ir = ib[(ll)f << 12];
      float iu = ib[(ll)(f + 64) << 12];
      float im = ib[(ll)(f + 128) << 12];
      float rr = 1.f / (1.f + __expf(-(ir + hr)));
      float uu = 1.f / (1.f + __expf(-(iu + hu)));
      float m = im + rr * hm;
      m = m >= 0.f ? m : 0.2f * m;
      float h0 = hp[(ll)f << 12];
      float hn = uu * h0 + (1.f - uu) * m;
      ob[(ll)f << 12] = hn;
      hn4[r] = hn;
    }
    st4(hc + ft * 16 + q * 4, hn4[0], hn4[1], hn4[2], hn4[3]);
  }
}

// ---------------------------------------------------------------------------
extern "C" void kernel_launch(void* const* d_in, const int* in_sizes, int n_in,
                              void* d_out, int out_size, void* d_ws, size_t ws_size,
                              hipStream_t stream) {
  const float* x      = (const float*)d_in[0];
  const float* W_down = (const float*)d_in[1];
  const float* b_down = (const float*)d_in[2];
  const float* W_i2h  = (const float*)d_in[3];
  const float* b_i2h  = (const float*)d_in[4];
  const float* W_i2f  = (const float*)d_in[5];
  const float* b_i2f  = (const float*)d_in[6];
  const float* W_h2f  = (const float*)d_in[7];
  const float* b_h2f  = (const float*)d_in[8];
  const float* W_flow = (const float*)d_in[9];
  const float* b_flow = (const float*)d_in[10];
  const float* W_ret  = (const float*)d_in[11];
  const float* b_ret  = (const float*)d_in[12];
  float* out = (float*)d_out;

  char* p = (char*)d_ws;
  char* pend = p + ws_size;
  auto alloc = [&](ll bytes) { char* r = p; p += (bytes + 255) & ~255LL; return r; };

  float*  Wd2    = (float*)alloc(147456LL * 4);
  float*  i2h_t  = (float*)alloc((ll)NB * 192 * HWSZ * 4);
  float*  flowsb = (float*)alloc((ll)NB * 10 * HWSZ * 4);
  float*  hzero  = (float*)alloc((ll)NB * NF * HWSZ * 4);
  __bf16* seq    = (__bf16*)alloc((ll)NT * NB * HWSZ * 64 * 2);
  __bf16* f1buf  = (__bf16*)alloc((ll)NB * HWSZ * 32 * 2);
  __bf16* warpedb= (__bf16*)alloc((ll)NB * HWSZ * 320 * 2);
  __bf16* hzb    = (__bf16*)alloc((ll)NB * HWSZ * 64 * 2);
  __bf16* hbufA  = (__bf16*)alloc((ll)NB * HWSZ * 64 * 2);
  __bf16* hbufB  = (__bf16*)alloc((ll)NB * HWSZ * 64 * 2);
  __bf16* Ai2h   = (__bf16*)alloc(110592LL * 2);
  __bf16* Af     = (__bf16*)alloc(102400LL * 2);
  __bf16* Afl    = (__bf16*)alloc(12800LL * 2);
  __bf16* Aret   = (__bf16*)alloc(61440LL * 2);
  if (p > pend) return;

  hipMemsetAsync(hzero, 0, (size_t)NB * NF * HWSZ * 4, stream);
  hipMemsetAsync(hzb, 0, (size_t)NB * HWSZ * 64 * 2, stream);

  k_prep<<<1698, 256, 0, stream>>>(W_down, W_i2h, W_i2f, W_h2f, W_flow, W_ret,
                                   Wd2, Ai2h, Af, Afl, Aret);
  k_down<<<NB * 64, 256, 0, stream>>>(x, Wd2, b_down, seq);

  const ll out_hsb = (ll)NT * NF * HWSZ;
  for (int t = 0; t < NT; ++t) {
    const __bf16* xt = seq + (ll)t * NB * HWSZ * 64;
    const __bf16* hb = (t == 0) ? hzb : ((t & 1) ? hbufA : hbufB);
    __bf16* hbc = (t & 1) ? hbufB : hbufA;
    const float* hpf;
    ll hsb;
    if (t == 0) { hpf = hzero; hsb = (ll)NF * HWSZ; }
    else        { hpf = out + (ll)(t - 1) * NF * HWSZ; hsb = out_hsb; }

    k_i2h<<<NB * 64, 256, 0, stream>>>(xt, Ai2h, b_i2h, i2h_t);
    k_f1<<<NB * 64, 256, 0, stream>>>(xt, hb, Af, b_i2f, b_h2f, f1buf);
    k_flow<<<NB * 64, 256, 0, stream>>>(f1buf, Afl, b_flow, flowsb);
    k_warp<<<NB * 64, 256, 0, stream>>>(flowsb, hb, warpedb);
    k_retgate<<<NB * 64, 256, 0, stream>>>(warpedb, Aret, b_ret, i2h_t,
                                           hpf, hsb,
                                           out + (ll)t * NF * HWSZ, out_hsb, hbc);
  }
}

// Round 3
// 1504.175 us; speedup vs baseline: 10.6438x; 1.6837x over previous
//
#include <hip/hip_runtime.h>
#include <cstdint>

typedef long long ll;
typedef __bf16 bf16x8 __attribute__((ext_vector_type(8)));
typedef float f32x4 __attribute__((ext_vector_type(4)));
typedef unsigned int u32x4 __attribute__((ext_vector_type(4)));

#define NB 8
#define NT 12
#define NF 64
#define HWSZ 4096

struct alignas(8)  bh4 { __bf16 h[4]; };
struct alignas(16) bh8 { __bf16 h[8]; };

static __device__ inline f32x4 mfma16(bf16x8 a, bf16x8 b, f32x4 c) {
  return __builtin_amdgcn_mfma_f32_16x16x32_bf16(a, b, c, 0, 0, 0);
}
static __device__ inline bf16x8 ld8(const __bf16* p) {
  u32x4 u = *(const u32x4*)p;
  return __builtin_bit_cast(bf16x8, u);
}
static __device__ inline void st4(__bf16* p, float a0, float a1, float a2, float a3) {
  bh4 t; t.h[0] = (__bf16)a0; t.h[1] = (__bf16)a1; t.h[2] = (__bf16)a2; t.h[3] = (__bf16)a3;
  *(bh4*)p = t;
}
static __device__ inline float lky(float a) { return a >= 0.f ? a : 0.2f * a; }

// Stage one row of a 64-ch NHWC bf16 map into granule-major LDS [8][W][8].
// xi = x_real + HALO. grow==null -> zeros. Halo slots zeroed (xi=h or 64+h).
template<int W, int HALO>
static __device__ void stage8(__bf16* dst, const __bf16* grow) {
  int tid = threadIdx.x;
  u32x4 zz = {0u, 0u, 0u, 0u};
  #pragma unroll
  for (int it = 0; it < 2; ++it) {
    int i = tid + it * 256;
    int xr = i >> 3, g = i & 7, xi = xr + HALO;
    u32x4 v = zz;
    if (grow) v = *(const u32x4*)(grow + xr * 64 + g * 8);
    *(u32x4*)(dst + (g * W + xi) * 8) = v;
  }
  if (tid < 16 * HALO) {
    int h = tid >> 3, g = tid & 7;
    int xi = (h < HALO) ? h : 64 + h;
    *(u32x4*)(dst + (g * W + xi) * 8) = zz;
  }
}

// Stage one row of a 32-ch NHWC bf16 map into granule-major LDS [4][W][8].
template<int W, int HALO>
static __device__ void stage4(__bf16* dst, const __bf16* grow) {
  int tid = threadIdx.x;
  u32x4 zz = {0u, 0u, 0u, 0u};
  {
    int xr = tid >> 2, g = tid & 3, xi = xr + HALO;
    u32x4 v = zz;
    if (grow) v = *(const u32x4*)(grow + xr * 32 + g * 8);
    *(u32x4*)(dst + (g * W + xi) * 8) = v;
  }
  if (tid < 8 * HALO) {
    int h = tid >> 2, g = tid & 3;
    int xi = (h < HALO) ? h : 64 + h;
    *(u32x4*)(dst + (g * W + xi) * 8) = zz;
  }
}

// ---------------------------------------------------------------------------
// Weight pre-transform: bf16 fragment-friendly layouts.
__global__ __launch_bounds__(256) void k_prep(
    const float* __restrict__ Wd, const float* __restrict__ Wc,
    const float* __restrict__ Wi, const float* __restrict__ Wh,
    const float* __restrict__ Wfl, const float* __restrict__ Wret,
    __bf16* __restrict__ Adown, __bf16* __restrict__ Ai2h,
    __bf16* __restrict__ Afi, __bf16* __restrict__ Afh,
    __bf16* __restrict__ Afl, __bf16* __restrict__ Aret) {
  int n = blockIdx.x * 256 + threadIdx.x;
  if (n < 147456) {                            // Adown[oc][k] (natural order)
    Adown[n] = (__bf16)Wd[n];
  } else if (n < 258048) {                     // Ai2h[tap][o192][c64]
    int i = n - 147456;
    int tap = i / 12288, o = (i % 12288) / 64, c = i % 64;
    Ai2h[i] = (__bf16)Wc[(o * 64 + c) * 9 + tap];
  } else if (n < 309248) {                     // Afi[tap][o32][c64]
    int i = n - 258048;
    int tap = i / 2048, o = (i % 2048) / 64, c = i % 64;
    Afi[i] = (__bf16)Wi[(o * 64 + c) * 25 + tap];
  } else if (n < 360448) {                     // Afh[tap][o32][c64]
    int i = n - 309248;
    int tap = i / 2048, o = (i % 2048) / 64, c = i % 64;
    Afh[i] = (__bf16)Wh[(o * 64 + c) * 25 + tap];
  } else if (n < 373248) {                     // Afl[tap][o16 pad][c32]
    int i = n - 360448;
    int tap = i / 512, o = (i % 512) / 32, c = i % 32;
    Afl[i] = (__bf16)(o < 10 ? Wfl[(o * 32 + c) * 25 + tap] : 0.f);
  } else if (n < 434688) {                     // Aret[o192][c320]
    Aret[n - 373248] = (__bf16)Wret[n - 373248];
  }
}

// ---------------------------------------------------------------------------
// Downsample conv as MFMA implicit GEMM. Grid (b,y,zQ): zQ splits M=768 into 4.
// LDS tile [12ic][4ky][130xi] bf16; B-frags built by 8x u16 tap-gather.
__global__ __launch_bounds__(256) void k_down(
    const float* __restrict__ x, const __bf16* __restrict__ Adown,
    const float* __restrict__ bd, __bf16* __restrict__ seq) {
  __shared__ __bf16 smd[6240];
  int bi = blockIdx.x;
  int zQ = bi & 3, y = (bi >> 2) & 63, b = bi >> 8;
  int tid = threadIdx.x;
  for (int i = tid; i < 6240; i += 256) {
    int ic = i / 520, rem = i % 520, ky = rem / 130, xi = rem % 130;
    int ix = xi - 1, iy = 2 * y - 1 + ky;
    float v = (ix >= 0 && ix < 128 && iy >= 0 && iy < 128)
                  ? x[(((ll)(b * 12 + ic) * 128 + iy) << 7) + ix] : 0.f;
    smd[i] = (__bf16)v;
  }
  __syncthreads();
  int wv = __builtin_amdgcn_readfirstlane(tid >> 6);
  int lane = tid & 63, q = lane >> 4, lr = lane & 15;
  int px = wv * 16 + lr;
  f32x4 zv = {0.f, 0.f, 0.f, 0.f};
  f32x4 acc[12];
  #pragma unroll
  for (int mt = 0; mt < 12; ++mt) acc[mt] = zv;

  for (int ks = 0; ks < 6; ++ks) {
    int k0 = ks * 32 + q * 8;
    int ic = k0 >> 4, ky0 = (k0 >> 2) & 3;
    const __bf16* rp = smd + (ic * 4 + ky0) * 130 + 2 * px;
    bh8 bb;
    #pragma unroll
    for (int j = 0; j < 8; ++j)
      bb.h[j] = rp[(j >> 2) * 130 + (j & 3)];
    bf16x8 bfr = __builtin_bit_cast(bf16x8, bb);
    #pragma unroll
    for (int mt = 0; mt < 12; ++mt) {
      bf16x8 afr = ld8(Adown + ((ll)(zQ * 192 + mt * 16 + lr) * 192 + k0));
      acc[mt] = mfma16(afr, bfr, acc[mt]);
    }
  }
  #pragma unroll
  for (int mt = 0; mt < 12; ++mt) {
    int t_idx = zQ * 3 + (mt >> 2);
    int f0 = (mt & 3) * 16 + q * 4;
    float v[4];
    #pragma unroll
    for (int r = 0; r < 4; ++r)
      v[r] = lky(acc[mt][r] + bd[zQ * 192 + mt * 16 + q * 4 + r]);
    st4(seq + (((ll)(t_idx * NB + b) * 4096 + y * 64 + px) * 64 + f0),
        v[0], v[1], v[2], v[3]);
  }
}

// ---------------------------------------------------------------------------
// i2h 3x3 conv, all timesteps. Block = (t,b,ypair): 2 output rows, 4 input rows
// staged [4][8][67][8]. Wave: row (wv>>1), M-half (wv&1): 6mt x 4nt, 432 MFMA.
// Out bf16 [t][b][y][x][192] with bias.
__global__ __launch_bounds__(256) void k_i2h_all(
    const __bf16* __restrict__ seq0, const __bf16* __restrict__ A,
    const float* __restrict__ bc, __bf16* __restrict__ out0) {
  __shared__ __align__(16) __bf16 sm[4 * 8 * 67 * 8];
  int bi = blockIdx.x;
  int t = bi >> 8, rem = bi & 255;
  int yp = rem & 31, b = rem >> 5;
  int y0 = yp * 2;
  const __bf16* xt = seq0 + (ll)(t * NB + b) * (4096 * 64);
  #pragma unroll
  for (int r = 0; r < 4; ++r) {
    int yr = y0 - 1 + r;
    stage8<67, 1>(sm + r * (8 * 67 * 8),
                  (yr >= 0 && yr < 64) ? xt + (ll)yr * 64 * 64 : nullptr);
  }
  __syncthreads();
  int tid = threadIdx.x;
  int wv = __builtin_amdgcn_readfirstlane(tid >> 6);
  int lane = tid & 63, q = lane >> 4, lr = lane & 15;
  int rsel = wv >> 1, mh = wv & 1;
  f32x4 zv = {0.f, 0.f, 0.f, 0.f};
  f32x4 acc[6][4];
  #pragma unroll
  for (int mt = 0; mt < 6; ++mt)
    #pragma unroll
    for (int nt = 0; nt < 4; ++nt) acc[mt][nt] = zv;

  #pragma unroll
  for (int tap = 0; tap < 9; ++tap) {
    int ky = tap / 3, kx = tap % 3;
    int s = rsel + ky;
    #pragma unroll
    for (int ks = 0; ks < 2; ++ks) {
      bf16x8 bfr[4];
      #pragma unroll
      for (int nt = 0; nt < 4; ++nt)
        bfr[nt] = ld8(sm + (((s * 8 + ks * 4 + q) * 67) + nt * 16 + lr + kx) * 8);
      #pragma unroll
      for (int mt = 0; mt < 6; ++mt) {
        bf16x8 afr = ld8(A + ((ll)(tap * 192 + (mh * 6 + mt) * 16 + lr) * 64 +
                              ks * 32 + q * 8));
        #pragma unroll
        for (int nt = 0; nt < 4; ++nt)
          acc[mt][nt] = mfma16(afr, bfr[nt], acc[mt][nt]);
      }
    }
  }
  int yo = y0 + rsel;
  #pragma unroll
  for (int nt = 0; nt < 4; ++nt) {
    int px = nt * 16 + lr;
    __bf16* op = out0 + ((ll)(t * NB + b) * 4096 + yo * 64 + px) * 192;
    #pragma unroll
    for (int mt = 0; mt < 6; ++mt) {
      int oc0 = (mh * 6 + mt) * 16 + q * 4;
      #pragma unroll
      for (int r = 0; r < 4; ++r) {}
      st4(op + oc0, acc[mt][nt][0] + bc[oc0],
                    acc[mt][nt][1] + bc[oc0 + 1],
                    acc[mt][nt][2] + bc[oc0 + 2],
                    acc[mt][nt][3] + bc[oc0 + 3]);
    }
  }
}

// ---------------------------------------------------------------------------
// i2f 5x5 conv, all timesteps, NO bias/activation. Block (t,b,y); 5 rows staged
// [5][8][69][8]. Wave: own nt, 2 mt, 25 taps x 2 ks. Out bf16 [t][b][y][x][32].
__global__ __launch_bounds__(256) void k_i2f_all(
    const __bf16* __restrict__ seq0, const __bf16* __restrict__ A,
    __bf16* __restrict__ out0) {
  __shared__ __align__(16) __bf16 sm[5 * 8 * 69 * 8];
  int bi = blockIdx.x;
  int t = bi >> 9, rem = bi & 511;
  int y = rem & 63, b = rem >> 6;
  const __bf16* xt = seq0 + (ll)(t * NB + b) * (4096 * 64);
  #pragma unroll
  for (int r = 0; r < 5; ++r) {
    int yr = y - 2 + r;
    stage8<69, 2>(sm + r * (8 * 69 * 8),
                  (yr >= 0 && yr < 64) ? xt + (ll)yr * 64 * 64 : nullptr);
  }
  __syncthreads();
  int tid = threadIdx.x;
  int wv = __builtin_amdgcn_readfirstlane(tid >> 6);
  int lane = tid & 63, q = lane >> 4, lr = lane & 15;
  int px = wv * 16 + lr;
  f32x4 zv = {0.f, 0.f, 0.f, 0.f};
  f32x4 acc[2] = {zv, zv};
  #pragma unroll
  for (int tap = 0; tap < 25; ++tap) {
    int ky = tap / 5, kx = tap % 5;
    #pragma unroll
    for (int ks = 0; ks < 2; ++ks) {
      bf16x8 bfr = ld8(sm + (((ky * 8 + ks * 4 + q) * 69) + px + kx) * 8);
      #pragma unroll
      for (int mt = 0; mt < 2; ++mt) {
        bf16x8 afr = ld8(A + ((ll)(tap * 32 + mt * 16 + lr) * 64 + ks * 32 + q * 8));
        acc[mt] = mfma16(afr, bfr, acc[mt]);
      }
    }
  }
  __bf16* op = out0 + ((ll)(t * NB + b) * 4096 + y * 64 + px) * 32;
  #pragma unroll
  for (int mt = 0; mt < 2; ++mt) {
    int oc0 = mt * 16 + q * 4;
    st4(op + oc0, acc[mt][0], acc[mt][1], acc[mt][2], acc[mt][3]);
  }
}

// ---------------------------------------------------------------------------
// Per-step: f1 = leaky(i2f_t + bi + h2f(h) + bh). h from bf16 NHWC hb.
__global__ __launch_bounds__(256) void k_h2f(
    const __bf16* __restrict__ hb, const __bf16* __restrict__ A,
    const float* __restrict__ bi, const float* __restrict__ bh,
    const __bf16* __restrict__ i2f_t, __bf16* __restrict__ f1buf) {
  __shared__ __align__(16) __bf16 sm[5 * 8 * 69 * 8];
  int bi_ = blockIdx.x;
  int y = bi_ & 63, b = bi_ >> 6;
  #pragma unroll
  for (int r = 0; r < 5; ++r) {
    int yr = y - 2 + r;
    stage8<69, 2>(sm + r * (8 * 69 * 8),
                  (yr >= 0 && yr < 64) ? hb + ((ll)(b * 64 + yr) * 64) * 64 : nullptr);
  }
  __syncthreads();
  int tid = threadIdx.x;
  int wv = __builtin_amdgcn_readfirstlane(tid >> 6);
  int lane = tid & 63, q = lane >> 4, lr = lane & 15;
  int px = wv * 16 + lr;
  f32x4 zv = {0.f, 0.f, 0.f, 0.f};
  f32x4 acc[2] = {zv, zv};
  #pragma unroll
  for (int tap = 0; tap < 25; ++tap) {
    int ky = tap / 5, kx = tap % 5;
    #pragma unroll
    for (int ks = 0; ks < 2; ++ks) {
      bf16x8 bfr = ld8(sm + (((ky * 8 + ks * 4 + q) * 69) + px + kx) * 8);
      #pragma unroll
      for (int mt = 0; mt < 2; ++mt) {
        bf16x8 afr = ld8(A + ((ll)(tap * 32 + mt * 16 + lr) * 64 + ks * 32 + q * 8));
        acc[mt] = mfma16(afr, bfr, acc[mt]);
      }
    }
  }
  const __bf16* ip = i2f_t + ((ll)(b * 64 + y) * 64 + px) * 32;
  __bf16* op = f1buf + ((ll)(b * 64 + y) * 64 + px) * 32;
  #pragma unroll
  for (int mt = 0; mt < 2; ++mt) {
    int oc0 = mt * 16 + q * 4;
    bh4 iv = *(const bh4*)(ip + oc0);
    float v[4];
    #pragma unroll
    for (int r = 0; r < 4; ++r)
      v[r] = lky(acc[mt][r] + (float)iv.h[r] + bi[oc0 + r] + bh[oc0 + r]);
    st4(op + oc0, v[0], v[1], v[2], v[3]);
  }
}

// ---------------------------------------------------------------------------
// Per-step fused: flow conv -> bilinear warp -> ret 1x1 GEMM -> GRU gates.
__global__ __launch_bounds__(256) void k_fwr(
    const __bf16* __restrict__ f1buf, const __bf16* __restrict__ Afl,
    const float* __restrict__ bfl, const __bf16* __restrict__ hb,
    const __bf16* __restrict__ Aret, const float* __restrict__ br,
    const __bf16* __restrict__ i2h_t, const float* __restrict__ hprevf,
    int t0, float* __restrict__ outp, ll osb, __bf16* __restrict__ hbc) {
  // LDS: f1 tile [5][4][69][8] (11040) | warped [40][65][8] (20800). flows f32
  // [64][17] overlays the f1 region after the flow conv.
  __shared__ __align__(16) __bf16 smem[11040 + 20800];
  __bf16* f1l = smem;
  __bf16* wrp = smem + 11040;
  float* flows = (float*)smem;

  int bi = blockIdx.x;
  int y = bi & 63, b = bi >> 6;
  int tid = threadIdx.x;
  int wv = __builtin_amdgcn_readfirstlane(tid >> 6);
  int lane = tid & 63, q = lane >> 4, lr = lane & 15;

  // phase 1: stage f1 rows y-2..y+2
  #pragma unroll
  for (int r = 0; r < 5; ++r) {
    int yr = y - 2 + r;
    stage4<69, 2>(f1l + r * (4 * 69 * 8),
                  (yr >= 0 && yr < 64) ? f1buf + ((ll)(b * 64 + yr) * 64) * 32 : nullptr);
  }
  __syncthreads();

  // phase 2: flow conv (M=16, 10 used; K=25x32)
  int px = wv * 16 + lr;
  f32x4 acc1 = {0.f, 0.f, 0.f, 0.f};
  #pragma unroll
  for (int tap = 0; tap < 25; ++tap) {
    int ky = tap / 5, kx = tap % 5;
    bf16x8 bfr = ld8(f1l + (((ky * 4 + q) * 69) + px + kx) * 8);
    bf16x8 afr = ld8(Afl + ((ll)(tap * 16 + lr) * 32 + q * 8));
    acc1 = mfma16(afr, bfr, acc1);
  }
  __syncthreads();  // all f1 reads done; safe to overlay flows
  #pragma unroll
  for (int r = 0; r < 4; ++r) {
    int oc = q * 4 + r;
    float v = acc1[r] + (oc < 10 ? bfl[oc] : 0.f);
    flows[px * 17 + oc] = v;
  }
  __syncthreads();

  // phase 3: warp 5 trajectories into wrp [G=l*8+cg'][65][8]
  {
    int xw = tid & 63, cg = tid >> 6;
    const __bf16* hbb = hb + ((ll)b << 18);
    #pragma unroll
    for (int l = 0; l < 5; ++l) {
      float fx = flows[xw * 17 + 2 * l];
      float fy = flows[xw * 17 + 2 * l + 1];
      float pxf = (float)xw - fx, pyf = (float)y - fy;
      float x0f = floorf(pxf), y0f = floorf(pyf);
      int x0 = (int)x0f, y0 = (int)y0f, x1 = x0 + 1, y1 = y0 + 1;
      float dx = pxf - x0f, dy = pyf - y0f;
      bool vx0 = x0 >= 0 && x0 <= 63, vx1 = x1 >= 0 && x1 <= 63;
      bool vy0 = y0 >= 0 && y0 <= 63, vy1 = y1 >= 0 && y1 <= 63;
      float wA = (vx0 && vy0) ? (1.f - dx) * (1.f - dy) : 0.f;
      float wB = (vx0 && vy1) ? (1.f - dx) * dy : 0.f;
      float wC = (vx1 && vy0) ? dx * (1.f - dy) : 0.f;
      float wD = (vx1 && vy1) ? dx * dy : 0.f;
      int cx0 = min(max(x0, 0), 63), cx1 = min(max(x1, 0), 63);
      int cy0 = min(max(y0, 0), 63), cy1 = min(max(y1, 0), 63);
      int o00 = (cy0 * 64 + cx0) * 64, o10 = (cy1 * 64 + cx0) * 64;
      int o01 = (cy0 * 64 + cx1) * 64, o11 = (cy1 * 64 + cx1) * 64;
      #pragma unroll
      for (int it = 0; it < 2; ++it) {
        int cgp = cg + it * 4;
        int c0 = cgp * 8;
        bf16x8 aA = ld8(hbb + o00 + c0), aB = ld8(hbb + o10 + c0);
        bf16x8 aC = ld8(hbb + o01 + c0), aD = ld8(hbb + o11 + c0);
        bh8 ov;
        #pragma unroll
        for (int i = 0; i < 8; ++i)
          ov.h[i] = (__bf16)(wA * (float)aA[i] + wB * (float)aB[i] +
                             wC * (float)aC[i] + wD * (float)aD[i]);
        *(bh8*)(wrp + ((l * 8 + cgp) * 65 + xw) * 8) = ov;
      }
    }
  }
  __syncthreads();

  // phase 4: ret 1x1 GEMM (M=192, K=320)
  f32x4 zv = {0.f, 0.f, 0.f, 0.f};
  f32x4 acc[12];
  #pragma unroll
  for (int mt = 0; mt < 12; ++mt) acc[mt] = zv;
  #pragma unroll
  for (int ks = 0; ks < 10; ++ks) {
    bf16x8 bfr = ld8(wrp + (((ks * 4 + q) * 65) + px) * 8);
    #pragma unroll
    for (int mt = 0; mt < 12; ++mt) {
      bf16x8 afr = ld8(Aret + ((ll)(mt * 16 + lr) * 320 + ks * 32 + q * 8));
      acc[mt] = mfma16(afr, bfr, acc[mt]);
    }
  }

  // phase 5: gates
  const __bf16* ih = i2h_t + ((ll)(b * 64 + y) * 64 + px) * 192;
  const float* hp = hprevf + (ll)b * osb + y * 64 + px;
  float* ob = outp + (ll)b * osb + y * 64 + px;
  __bf16* hc = hbc + ((ll)(b * 64 + y) * 64 + px) * 64;
  #pragma unroll
  for (int ft = 0; ft < 4; ++ft) {
    int f0 = ft * 16 + q * 4;
    bh4 irv = *(const bh4*)(ih + f0);
    bh4 iuv = *(const bh4*)(ih + f0 + 64);
    bh4 imv = *(const bh4*)(ih + f0 + 128);
    float hn4[4];
    #pragma unroll
    for (int r = 0; r < 4; ++r) {
      int f = f0 + r;
      float hr = acc[ft][r] + br[f];
      float hu = acc[ft + 4][r] + br[f + 64];
      float hm = acc[ft + 8][r] + br[f + 128];
      float rr = 1.f / (1.f + __expf(-((float)irv.h[r] + hr)));
      float uu = 1.f / (1.f + __expf(-((float)iuv.h[r] + hu)));
      float m = lky((float)imv.h[r] + rr * hm);
      float h0 = t0 ? 0.f : hp[(ll)f << 12];
      float hn = uu * h0 + (1.f - uu) * m;
      ob[(ll)f << 12] = hn;
      hn4[r] = hn;
    }
    st4(hc + f0, hn4[0], hn4[1], hn4[2], hn4[3]);
  }
}

// ---------------------------------------------------------------------------
extern "C" void kernel_launch(void* const* d_in, const int* in_sizes, int n_in,
                              void* d_out, int out_size, void* d_ws, size_t ws_size,
                              hipStream_t stream) {
  const float* x      = (const float*)d_in[0];
  const float* W_down = (const float*)d_in[1];
  const float* b_down = (const float*)d_in[2];
  const float* W_i2h  = (const float*)d_in[3];
  const float* b_i2h  = (const float*)d_in[4];
  const float* W_i2f  = (const float*)d_in[5];
  const float* b_i2f  = (const float*)d_in[6];
  const float* W_h2f  = (const float*)d_in[7];
  const float* b_h2f  = (const float*)d_in[8];
  const float* W_flow = (const float*)d_in[9];
  const float* b_flow = (const float*)d_in[10];
  const float* W_ret  = (const float*)d_in[11];
  const float* b_ret  = (const float*)d_in[12];
  float* out = (float*)d_out;

  const ll I2H_T = (ll)NB * 4096 * 192;   // per-t elements
  const ll I2F_T = (ll)NB * 4096 * 32;
  const ll H_N   = (ll)NB * 4096 * 64;

  // fixed allocations (bytes)
  auto align256 = [](ll v) { return (v + 255) & ~255LL; };
  ll fixed = 0;
  fixed += align256(147456LL * 2);          // Adown
  fixed += align256(110592LL * 2);          // Ai2h
  fixed += align256(51200LL * 2);           // Afi
  fixed += align256(51200LL * 2);           // Afh
  fixed += align256(12800LL * 2);           // Afl
  fixed += align256(61440LL * 2);           // Aret
  fixed += align256((ll)NT * NB * 4096 * 64 * 2);  // seq
  fixed += align256((ll)NB * 4096 * 32 * 2);       // f1buf
  fixed += align256(H_N * 2) * 3;                  // hzb, hA, hB
  ll need_full = fixed + align256(NT * I2H_T * 2) + align256(NT * I2F_T * 2);
  int fits = (need_full <= (ll)ws_size);
  int slabT = fits ? NT : 1;

  char* p = (char*)d_ws;
  auto alloc = [&](ll bytes) { char* r = p; p += (bytes + 255) & ~255LL; return r; };
  __bf16* Adown  = (__bf16*)alloc(147456LL * 2);
  __bf16* Ai2h   = (__bf16*)alloc(110592LL * 2);
  __bf16* Afi    = (__bf16*)alloc(51200LL * 2);
  __bf16* Afh    = (__bf16*)alloc(51200LL * 2);
  __bf16* Afl    = (__bf16*)alloc(12800LL * 2);
  __bf16* Aret   = (__bf16*)alloc(61440LL * 2);
  __bf16* seq    = (__bf16*)alloc((ll)NT * NB * 4096 * 64 * 2);
  __bf16* f1buf  = (__bf16*)alloc((ll)NB * 4096 * 32 * 2);
  __bf16* hzb    = (__bf16*)alloc(H_N * 2);
  __bf16* hbufA  = (__bf16*)alloc(H_N * 2);
  __bf16* hbufB  = (__bf16*)alloc(H_N * 2);
  __bf16* i2h_sl = (__bf16*)alloc(slabT * I2H_T * 2);
  __bf16* i2f_sl = (__bf16*)alloc(slabT * I2F_T * 2);
  if (p > (char*)d_ws + ws_size) return;

  hipMemsetAsync(hzb, 0, (size_t)H_N * 2, stream);

  k_prep<<<1698, 256, 0, stream>>>(W_down, W_i2h, W_i2f, W_h2f, W_flow, W_ret,
                                   Adown, Ai2h, Afi, Afh, Afl, Aret);
  k_down<<<NB * 64 * 4, 256, 0, stream>>>(x, Adown, b_down, seq);

  if (fits) {
    k_i2h_all<<<NT * 256, 256, 0, stream>>>(seq, Ai2h, b_i2h, i2h_sl);
    k_i2f_all<<<NT * 512, 256, 0, stream>>>(seq, Afi, i2f_sl);
  }

  const ll osb = (ll)NT * NF * HWSZ;
  for (int t = 0; t < NT; ++t) {
    const __bf16* xt0 = seq + (ll)t * NB * 4096 * 64;
    if (!fits) {
      k_i2h_all<<<256, 256, 0, stream>>>(xt0, Ai2h, b_i2h, i2h_sl);
      k_i2f_all<<<512, 256, 0, stream>>>(xt0, Afi, i2f_sl);
    }
    int ti = fits ? t : 0;
    const __bf16* hb = (t == 0) ? hzb : ((t & 1) ? hbufA : hbufB);
    __bf16* hbc = (t & 1) ? hbufB : hbufA;
    const float* hpf = (t == 0) ? out : out + (ll)(t - 1) * NF * HWSZ;

    k_h2f<<<NB * 64, 256, 0, stream>>>(hb, Afh, b_i2f, b_h2f,
                                       i2f_sl + (ll)ti * I2F_T, f1buf);
    k_fwr<<<NB * 64, 256, 0, stream>>>(f1buf, Afl, b_flow, hb, Aret, b_ret,
                                       i2h_sl + (ll)ti * I2H_T, hpf,
                                       (t == 0) ? 1 : 0,
                                       out + (ll)t * NF * HWSZ, osb, hbc);
  }
}

// Round 4
// 1206.147 us; speedup vs baseline: 13.2738x; 1.2471x over previous
//
#include <hip/hip_runtime.h>
#include <cstdint>

typedef long long ll;
typedef __bf16 bf16x8 __attribute__((ext_vector_type(8)));
typedef float f32x4 __attribute__((ext_vector_type(4)));
typedef unsigned int u32x4 __attribute__((ext_vector_type(4)));

#define NB 8
#define NT 12
#define NF 64
#define HWSZ 4096

struct alignas(8)  bh4 { __bf16 h[4]; };
struct alignas(16) bh8 { __bf16 h[8]; };

static __device__ inline f32x4 mfma16(bf16x8 a, bf16x8 b, f32x4 c) {
  return __builtin_amdgcn_mfma_f32_16x16x32_bf16(a, b, c, 0, 0, 0);
}
static __device__ inline bf16x8 ld8(const __bf16* p) {
  u32x4 u = *(const u32x4*)p;
  return __builtin_bit_cast(bf16x8, u);
}
static __device__ inline void st4(__bf16* p, float a0, float a1, float a2, float a3) {
  bh4 t; t.h[0] = (__bf16)a0; t.h[1] = (__bf16)a1; t.h[2] = (__bf16)a2; t.h[3] = (__bf16)a3;
  *(bh4*)p = t;
}
static __device__ inline float lky(float a) { return a >= 0.f ? a : 0.2f * a; }

// XCD-chunked swizzle (grid divisible by 8): neighbors share an XCD L2.
static __device__ inline int swz_bid() {
  int bid = blockIdx.x;
  return ((gridDim.x & 7) == 0) ? (bid & 7) * (gridDim.x >> 3) + (bid >> 3) : bid;
}

// Stage one row of a 64-ch NHWC bf16 map into LDS [g8][W][8] (full channels).
template<int W, int HALO>
static __device__ void stage8(__bf16* dst, const __bf16* grow) {
  int tid = threadIdx.x;
  u32x4 zz = {0u, 0u, 0u, 0u};
  #pragma unroll
  for (int it = 0; it < 2; ++it) {
    int i = tid + it * 256;
    int xr = i >> 3, g = i & 7, xi = xr + HALO;
    u32x4 v = zz;
    if (grow) v = *(const u32x4*)(grow + xr * 64 + g * 8);
    *(u32x4*)(dst + (g * W + xi) * 8) = v;
  }
  if (tid < 16 * HALO) {
    int h = tid >> 3, g = tid & 7;
    int xi = (h < HALO) ? h : 64 + h;
    *(u32x4*)(dst + (g * W + xi) * 8) = zz;
  }
}

// Stage one row, HALF the channels (granules goff..goff+3) into [g4][W][8].
template<int W, int HALO>
static __device__ void stage_half(__bf16* dst, const __bf16* grow, int goff) {
  int tid = threadIdx.x;
  u32x4 zz = {0u, 0u, 0u, 0u};
  {
    int xr = tid >> 2, g = tid & 3, xi = xr + HALO;
    u32x4 v = zz;
    if (grow) v = *(const u32x4*)(grow + xr * 64 + (goff + g) * 8);
    *(u32x4*)(dst + (g * W + xi) * 8) = v;
  }
  if (tid < 8 * HALO) {
    int h = tid >> 2, g = tid & 3;
    int xi = (h < HALO) ? h : 64 + h;
    *(u32x4*)(dst + (g * W + xi) * 8) = zz;
  }
}

// Stage one row of a 32-ch NHWC bf16 map into [g4][W][8].
template<int W, int HALO>
static __device__ void stage4(__bf16* dst, const __bf16* grow) {
  int tid = threadIdx.x;
  u32x4 zz = {0u, 0u, 0u, 0u};
  {
    int xr = tid >> 2, g = tid & 3, xi = xr + HALO;
    u32x4 v = zz;
    if (grow) v = *(const u32x4*)(grow + xr * 32 + g * 8);
    *(u32x4*)(dst + (g * W + xi) * 8) = v;
  }
  if (tid < 8 * HALO) {
    int h = tid >> 2, g = tid & 3;
    int xi = (h < HALO) ? h : 64 + h;
    *(u32x4*)(dst + (g * W + xi) * 8) = zz;
  }
}

// ---------------------------------------------------------------------------
// Weight pre-transform: bf16 fragment-friendly layouts.
__global__ __launch_bounds__(256) void k_prep(
    const float* __restrict__ Wd, const float* __restrict__ Wc,
    const float* __restrict__ Wi, const float* __restrict__ Wh,
    const float* __restrict__ Wfl, const float* __restrict__ Wret,
    __bf16* __restrict__ Adown, __bf16* __restrict__ Ai2h,
    __bf16* __restrict__ Afi, __bf16* __restrict__ Afh,
    __bf16* __restrict__ Afl, __bf16* __restrict__ Aret) {
  int n = blockIdx.x * 256 + threadIdx.x;
  if (n < 147456) {                            // Adown[oc][k]
    Adown[n] = (__bf16)Wd[n];
  } else if (n < 258048) {                     // Ai2h[tap][o192][c64]
    int i = n - 147456;
    int tap = i / 12288, o = (i % 12288) / 64, c = i % 64;
    Ai2h[i] = (__bf16)Wc[(o * 64 + c) * 9 + tap];
  } else if (n < 309248) {                     // Afi[tap][o32][c64]
    int i = n - 258048;
    int tap = i / 2048, o = (i % 2048) / 64, c = i % 64;
    Afi[i] = (__bf16)Wi[(o * 64 + c) * 25 + tap];
  } else if (n < 360448) {                     // Afh[tap][o32][c64]
    int i = n - 309248;
    int tap = i / 2048, o = (i % 2048) / 64, c = i % 64;
    Afh[i] = (__bf16)Wh[(o * 64 + c) * 25 + tap];
  } else if (n < 373248) {                     // Afl[tap][o16 pad][c32]
    int i = n - 360448;
    int tap = i / 512, o = (i % 512) / 32, c = i % 32;
    Afl[i] = (__bf16)(o < 10 ? Wfl[(o * 32 + c) * 25 + tap] : 0.f);
  } else if (n < 434688) {                     // Aret[o192][c320]
    Aret[n - 373248] = (__bf16)Wret[n - 373248];
  }
}

// ---------------------------------------------------------------------------
// Downsample conv as MFMA implicit GEMM. (b,y,zQ); zQ splits M=768 into 4.
__global__ __launch_bounds__(256) void k_down(
    const float* __restrict__ x, const __bf16* __restrict__ Adown,
    const float* __restrict__ bd, __bf16* __restrict__ seq) {
  __shared__ __bf16 smd[6240];
  int bi = swz_bid();
  int zQ = bi & 3, y = (bi >> 2) & 63, b = bi >> 8;
  int tid = threadIdx.x;
  for (int i = tid; i < 6240; i += 256) {
    int ic = i / 520, rem = i % 520, ky = rem / 130, xi = rem % 130;
    int ix = xi - 1, iy = 2 * y - 1 + ky;
    float v = (ix >= 0 && ix < 128 && iy >= 0 && iy < 128)
                  ? x[(((ll)(b * 12 + ic) * 128 + iy) << 7) + ix] : 0.f;
    smd[i] = (__bf16)v;
  }
  __syncthreads();
  int wv = __builtin_amdgcn_readfirstlane(tid >> 6);
  int lane = tid & 63, q = lane >> 4, lr = lane & 15;
  int px = wv * 16 + lr;
  f32x4 zv = {0.f, 0.f, 0.f, 0.f};
  f32x4 acc[12];
  #pragma unroll
  for (int mt = 0; mt < 12; ++mt) acc[mt] = zv;

  for (int ks = 0; ks < 6; ++ks) {
    int k0 = ks * 32 + q * 8;
    int ic = k0 >> 4, ky0 = (k0 >> 2) & 3;
    const __bf16* rp = smd + (ic * 4 + ky0) * 130 + 2 * px;
    bh8 bb;
    #pragma unroll
    for (int j = 0; j < 8; ++j)
      bb.h[j] = rp[(j >> 2) * 130 + (j & 3)];
    bf16x8 bfr = __builtin_bit_cast(bf16x8, bb);
    #pragma unroll
    for (int mt = 0; mt < 12; ++mt) {
      bf16x8 afr = ld8(Adown + ((ll)(zQ * 192 + mt * 16 + lr) * 192 + k0));
      acc[mt] = mfma16(afr, bfr, acc[mt]);
    }
  }
  #pragma unroll
  for (int mt = 0; mt < 12; ++mt) {
    int t_idx = zQ * 3 + (mt >> 2);
    int f0 = (mt & 3) * 16 + q * 4;
    float v[4];
    #pragma unroll
    for (int r = 0; r < 4; ++r)
      v[r] = lky(acc[mt][r] + bd[zQ * 192 + mt * 16 + q * 4 + r]);
    st4(seq + (((ll)(t_idx * NB + b) * 4096 + y * 64 + px) * 64 + f0),
        v[0], v[1], v[2], v[3]);
  }
}

// ---------------------------------------------------------------------------
// 5x5 conv over 64ch input, 32 oc. NR rows per block, wave owns x-quarter x
// all NR rows (B-tiles = rows -> 4x A-frag reuse). Two ks-half passes keep
// LDS at [NR+4][g4][69][8]. 2-stage prefetch pipeline; launch_bounds(256,2).
// FUSE: out = leaky(acc + addv + bi + bh) else raw acc. Out NHWC [tb][y][x][32].
template<bool FUSE, int NR>
__global__ __launch_bounds__(256, 2) void k_conv5(
    const __bf16* __restrict__ in0, const __bf16* __restrict__ A,
    const float* __restrict__ bi, const float* __restrict__ bh,
    const __bf16* __restrict__ addv, __bf16* __restrict__ out0) {
  constexpr int SR = NR + 4;
  __shared__ __align__(16) __bf16 sm[SR * 4 * 69 * 8];
  int bi_ = swz_bid();
  constexpr int YG = 64 / NR;
  int yg = bi_ % YG, tb = bi_ / YG;
  int y0 = yg * NR;
  const __bf16* base = in0 + (ll)tb * (4096 * 64);
  int tid = threadIdx.x;
  int wv = __builtin_amdgcn_readfirstlane(tid >> 6);
  int lane = tid & 63, q = lane >> 4, lr = lane & 15;
  int px = wv * 16 + lr;
  f32x4 zv = {0.f, 0.f, 0.f, 0.f};
  f32x4 acc[2][NR];
  #pragma unroll
  for (int mt = 0; mt < 2; ++mt)
    #pragma unroll
    for (int r = 0; r < NR; ++r) acc[mt][r] = zv;

  bf16x8 cb[NR], ca[2], nb[NR], na[2];
  auto loadk = [&](int tap, int ks, bf16x8* bb, bf16x8* aa) {
    int ky = tap / 5, kx = tap % 5;
    #pragma unroll
    for (int mt = 0; mt < 2; ++mt)
      aa[mt] = ld8(A + ((ll)(tap * 32 + mt * 16 + lr) * 64 + ks * 32 + q * 8));
    #pragma unroll
    for (int r = 0; r < NR; ++r)
      bb[r] = ld8(sm + (((r + ky) * 4 + q) * 69 + px + kx) * 8);
  };

  #pragma unroll
  for (int ks = 0; ks < 2; ++ks) {
    if (ks) __syncthreads();               // all reads of pass 0 done
    #pragma unroll
    for (int s = 0; s < SR; ++s) {
      int yr = y0 - 2 + s;
      stage_half<69, 2>(sm + s * (4 * 69 * 8),
                        (yr >= 0 && yr < 64) ? base + (ll)yr * 64 * 64 : nullptr,
                        ks * 4);
    }
    __syncthreads();
    loadk(0, ks, cb, ca);
    #pragma unroll
    for (int tap = 0; tap < 25; ++tap) {
      if (tap < 24) loadk(tap + 1, ks, nb, na);
      #pragma unroll
      for (int mt = 0; mt < 2; ++mt)
        #pragma unroll
        for (int r = 0; r < NR; ++r)
          acc[mt][r] = mfma16(ca[mt], cb[r], acc[mt][r]);
      #pragma unroll
      for (int r = 0; r < NR; ++r) cb[r] = nb[r];
      ca[0] = na[0]; ca[1] = na[1];
    }
  }

  #pragma unroll
  for (int r = 0; r < NR; ++r) {
    __bf16* op = out0 + ((ll)tb * 4096 + (y0 + r) * 64 + px) * 32;
    #pragma unroll
    for (int mt = 0; mt < 2; ++mt) {
      int oc0 = mt * 16 + q * 4;
      if (FUSE) {
        const __bf16* ip = addv + ((ll)tb * 4096 + (y0 + r) * 64 + px) * 32 + oc0;
        bh4 iv = *(const bh4*)ip;
        float v[4];
        #pragma unroll
        for (int rr = 0; rr < 4; ++rr)
          v[rr] = lky(acc[mt][r][rr] + (float)iv.h[rr] + bi[oc0 + rr] + bh[oc0 + rr]);
        st4(op + oc0, v[0], v[1], v[2], v[3]);
      } else {
        st4(op + oc0, acc[mt][r][0], acc[mt][r][1], acc[mt][r][2], acc[mt][r][3]);
      }
    }
  }
}

// ---------------------------------------------------------------------------
// i2h 3x3 conv: block = (tb, yp): 2 rows. Wave (mh, xh): 6mt x 2ntx x 2rows.
// LDS [s4][g8][67][8] = 34.3 KB, single stage. 2-stage prefetch pipeline.
__global__ __launch_bounds__(256, 2) void k_i2h2(
    const __bf16* __restrict__ in0, const __bf16* __restrict__ A,
    const float* __restrict__ bc, __bf16* __restrict__ out0) {
  __shared__ __align__(16) __bf16 sm[4 * 8 * 67 * 8];
  int bi_ = swz_bid();
  int yp = bi_ & 31, tb = bi_ >> 5;
  int y0 = yp * 2;
  const __bf16* base = in0 + (ll)tb * (4096 * 64);
  #pragma unroll
  for (int s = 0; s < 4; ++s) {
    int yr = y0 - 1 + s;
    stage8<67, 1>(sm + s * (8 * 67 * 8),
                  (yr >= 0 && yr < 64) ? base + (ll)yr * 64 * 64 : nullptr);
  }
  __syncthreads();
  int tid = threadIdx.x;
  int wv = __builtin_amdgcn_readfirstlane(tid >> 6);
  int lane = tid & 63, q = lane >> 4, lr = lane & 15;
  int mh = wv & 1, xh = wv >> 1;
  f32x4 zv = {0.f, 0.f, 0.f, 0.f};
  f32x4 acc[6][2][2];
  #pragma unroll
  for (int mt = 0; mt < 6; ++mt)
    #pragma unroll
    for (int nx = 0; nx < 2; ++nx)
      #pragma unroll
      for (int r = 0; r < 2; ++r) acc[mt][nx][r] = zv;

  bf16x8 cb[2][2], ca[6], nb[2][2], na[6];
  auto loadk = [&](int kk, bf16x8 bb[2][2], bf16x8* aa) {
    int ks = kk & 1, tap = kk >> 1;
    int ky = tap / 3, kx = tap % 3;
    int g = ks * 4 + q;
    #pragma unroll
    for (int mt = 0; mt < 6; ++mt)
      aa[mt] = ld8(A + ((ll)(tap * 192 + (mh * 6 + mt) * 16 + lr) * 64 +
                        ks * 32 + q * 8));
    #pragma unroll
    for (int nx = 0; nx < 2; ++nx)
      #pragma unroll
      for (int r = 0; r < 2; ++r)
        bb[nx][r] = ld8(sm + (((r + ky) * 8 + g) * 67 +
                              xh * 32 + nx * 16 + lr + kx) * 8);
  };

  loadk(0, cb, ca);
  #pragma unroll
  for (int kk = 0; kk < 18; ++kk) {
    if (kk < 17) loadk(kk + 1, nb, na);
    #pragma unroll
    for (int mt = 0; mt < 6; ++mt)
      #pragma unroll
      for (int nx = 0; nx < 2; ++nx)
        #pragma unroll
        for (int r = 0; r < 2; ++r)
          acc[mt][nx][r] = mfma16(ca[mt], cb[nx][r], acc[mt][nx][r]);
    #pragma unroll
    for (int nx = 0; nx < 2; ++nx)
      #pragma unroll
      for (int r = 0; r < 2; ++r) cb[nx][r] = nb[nx][r];
    #pragma unroll
    for (int mt = 0; mt < 6; ++mt) ca[mt] = na[mt];
  }

  #pragma unroll
  for (int nx = 0; nx < 2; ++nx) {
    int px = xh * 32 + nx * 16 + lr;
    #pragma unroll
    for (int r = 0; r < 2; ++r) {
      __bf16* op = out0 + ((ll)tb * 4096 + (y0 + r) * 64 + px) * 192;
      #pragma unroll
      for (int mt = 0; mt < 6; ++mt) {
        int oc0 = (mh * 6 + mt) * 16 + q * 4;
        st4(op + oc0, acc[mt][nx][r][0] + bc[oc0],
                      acc[mt][nx][r][1] + bc[oc0 + 1],
                      acc[mt][nx][r][2] + bc[oc0 + 2],
                      acc[mt][nx][r][3] + bc[oc0 + 3]);
      }
    }
  }
}

// ---------------------------------------------------------------------------
// Per-step fused: flow conv -> bilinear warp -> ret 1x1 GEMM -> GRU gates.
__global__ __launch_bounds__(256, 2) void k_fwr(
    const __bf16* __restrict__ f1buf, const __bf16* __restrict__ Afl,
    const float* __restrict__ bfl, const __bf16* __restrict__ hb,
    const __bf16* __restrict__ Aret, const float* __restrict__ br,
    const __bf16* __restrict__ i2h_t, const float* __restrict__ hprevf,
    int t0, float* __restrict__ outp, ll osb, __bf16* __restrict__ hbc) {
  __shared__ __align__(16) __bf16 smem[11040 + 20800];
  __bf16* f1l = smem;
  __bf16* wrp = smem + 11040;
  float* flows = (float*)smem;

  int bi = swz_bid();
  int y = bi & 63, b = bi >> 6;
  int tid = threadIdx.x;
  int wv = __builtin_amdgcn_readfirstlane(tid >> 6);
  int lane = tid & 63, q = lane >> 4, lr = lane & 15;

  #pragma unroll
  for (int r = 0; r < 5; ++r) {
    int yr = y - 2 + r;
    stage4<69, 2>(f1l + r * (4 * 69 * 8),
                  (yr >= 0 && yr < 64) ? f1buf + ((ll)(b * 64 + yr) * 64) * 32 : nullptr);
  }
  __syncthreads();

  // flow conv (M=16, 10 used; K=25x32)
  int px = wv * 16 + lr;
  f32x4 acc1 = {0.f, 0.f, 0.f, 0.f};
  #pragma unroll
  for (int tap = 0; tap < 25; ++tap) {
    int ky = tap / 5, kx = tap % 5;
    bf16x8 bfr = ld8(f1l + (((ky * 4 + q) * 69) + px + kx) * 8);
    bf16x8 afr = ld8(Afl + ((ll)(tap * 16 + lr) * 32 + q * 8));
    acc1 = mfma16(afr, bfr, acc1);
  }
  __syncthreads();
  #pragma unroll
  for (int r = 0; r < 4; ++r) {
    int oc = q * 4 + r;
    float v = acc1[r] + (oc < 10 ? bfl[oc] : 0.f);
    flows[px * 17 + oc] = v;
  }
  __syncthreads();

  // warp 5 trajectories into wrp [40][65][8]
  {
    int xw = tid & 63, cg = tid >> 6;
    const __bf16* hbb = hb + ((ll)b << 18);
    #pragma unroll
    for (int l = 0; l < 5; ++l) {
      float fx = flows[xw * 17 + 2 * l];
      float fy = flows[xw * 17 + 2 * l + 1];
      float pxf = (float)xw - fx, pyf = (float)y - fy;
      float x0f = floorf(pxf), y0f = floorf(pyf);
      int x0 = (int)x0f, y0 = (int)y0f, x1 = x0 + 1, y1 = y0 + 1;
      float dx = pxf - x0f, dy = pyf - y0f;
      bool vx0 = x0 >= 0 && x0 <= 63, vx1 = x1 >= 0 && x1 <= 63;
      bool vy0 = y0 >= 0 && y0 <= 63, vy1 = y1 >= 0 && y1 <= 63;
      float wA = (vx0 && vy0) ? (1.f - dx) * (1.f - dy) : 0.f;
      float wB = (vx0 && vy1) ? (1.f - dx) * dy : 0.f;
      float wC = (vx1 && vy0) ? dx * (1.f - dy) : 0.f;
      float wD = (vx1 && vy1) ? dx * dy : 0.f;
      int cx0 = min(max(x0, 0), 63), cx1 = min(max(x1, 0), 63);
      int cy0 = min(max(y0, 0), 63), cy1 = min(max(y1, 0), 63);
      int o00 = (cy0 * 64 + cx0) * 64, o10 = (cy1 * 64 + cx0) * 64;
      int o01 = (cy0 * 64 + cx1) * 64, o11 = (cy1 * 64 + cx1) * 64;
      #pragma unroll
      for (int it = 0; it < 2; ++it) {
        int cgp = cg + it * 4;
        int c0 = cgp * 8;
        bf16x8 aA = ld8(hbb + o00 + c0), aB = ld8(hbb + o10 + c0);
        bf16x8 aC = ld8(hbb + o01 + c0), aD = ld8(hbb + o11 + c0);
        bh8 ov;
        #pragma unroll
        for (int i = 0; i < 8; ++i)
          ov.h[i] = (__bf16)(wA * (float)aA[i] + wB * (float)aB[i] +
                             wC * (float)aC[i] + wD * (float)aD[i]);
        *(bh8*)(wrp + ((l * 8 + cgp) * 65 + xw) * 8) = ov;
      }
    }
  }
  __syncthreads();

  // ret 1x1 GEMM (M=192, K=320) with ks prefetch
  f32x4 zv = {0.f, 0.f, 0.f, 0.f};
  f32x4 acc[12];
  #pragma unroll
  for (int mt = 0; mt < 12; ++mt) acc[mt] = zv;
  bf16x8 cbf, nbf, caf[12], naf[12];
  auto loadr = [&](int ks, bf16x8& bb, bf16x8* aa) {
    bb = ld8(wrp + (((ks * 4 + q) * 65) + px) * 8);
    #pragma unroll
    for (int mt = 0; mt < 12; ++mt)
      aa[mt] = ld8(Aret + ((ll)(mt * 16 + lr) * 320 + ks * 32 + q * 8));
  };
  loadr(0, cbf, caf);
  #pragma unroll
  for (int ks = 0; ks < 10; ++ks) {
    if (ks < 9) loadr(ks + 1, nbf, naf);
    #pragma unroll
    for (int mt = 0; mt < 12; ++mt) acc[mt] = mfma16(caf[mt], cbf, acc[mt]);
    cbf = nbf;
    #pragma unroll
    for (int mt = 0; mt < 12; ++mt) caf[mt] = naf[mt];
  }

  // gates
  const __bf16* ih = i2h_t + ((ll)(b * 64 + y) * 64 + px) * 192;
  const float* hp = hprevf + (ll)b * osb + y * 64 + px;
  float* ob = outp + (ll)b * osb + y * 64 + px;
  __bf16* hc = hbc + ((ll)(b * 64 + y) * 64 + px) * 64;
  #pragma unroll
  for (int ft = 0; ft < 4; ++ft) {
    int f0 = ft * 16 + q * 4;
    bh4 irv = *(const bh4*)(ih + f0);
    bh4 iuv = *(const bh4*)(ih + f0 + 64);
    bh4 imv = *(const bh4*)(ih + f0 + 128);
    float hn4[4];
    #pragma unroll
    for (int r = 0; r < 4; ++r) {
      int f = f0 + r;
      float hr = acc[ft][r] + br[f];
      float hu = acc[ft + 4][r] + br[f + 64];
      float hm = acc[ft + 8][r] + br[f + 128];
      float rr = 1.f / (1.f + __expf(-((float)irv.h[r] + hr)));
      float uu = 1.f / (1.f + __expf(-((float)iuv.h[r] + hu)));
      float m = lky((float)imv.h[r] + rr * hm);
      float h0 = t0 ? 0.f : hp[(ll)f << 12];
      float hn = uu * h0 + (1.f - uu) * m;
      ob[(ll)f << 12] = hn;
      hn4[r] = hn;
    }
    st4(hc + f0, hn4[0], hn4[1], hn4[2], hn4[3]);
  }
}

// ---------------------------------------------------------------------------
extern "C" void kernel_launch(void* const* d_in, const int* in_sizes, int n_in,
                              void* d_out, int out_size, void* d_ws, size_t ws_size,
                              hipStream_t stream) {
  const float* x      = (const float*)d_in[0];
  const float* W_down = (const float*)d_in[1];
  const float* b_down = (const float*)d_in[2];
  const float* W_i2h  = (const float*)d_in[3];
  const float* b_i2h  = (const float*)d_in[4];
  const float* W_i2f  = (const float*)d_in[5];
  const float* b_i2f  = (const float*)d_in[6];
  const float* W_h2f  = (const float*)d_in[7];
  const float* b_h2f  = (const float*)d_in[8];
  const float* W_flow = (const float*)d_in[9];
  const float* b_flow = (const float*)d_in[10];
  const float* W_ret  = (const float*)d_in[11];
  const float* b_ret  = (const float*)d_in[12];
  float* out = (float*)d_out;

  const ll I2H_T = (ll)NB * 4096 * 192;
  const ll I2F_T = (ll)NB * 4096 * 32;
  const ll H_N   = (ll)NB * 4096 * 64;

  auto align256 = [](ll v) { return (v + 255) & ~255LL; };
  ll fixed = 0;
  fixed += align256(147456LL * 2);
  fixed += align256(110592LL * 2);
  fixed += align256(51200LL * 2);
  fixed += align256(51200LL * 2);
  fixed += align256(12800LL * 2);
  fixed += align256(61440LL * 2);
  fixed += align256((ll)NT * NB * 4096 * 64 * 2);
  fixed += align256((ll)NB * 4096 * 32 * 2);
  fixed += align256(H_N * 2) * 3;
  ll need_full = fixed + align256(NT * I2H_T * 2) + align256(NT * I2F_T * 2);
  int fits = (need_full <= (ll)ws_size);
  int slabT = fits ? NT : 1;

  char* p = (char*)d_ws;
  auto alloc = [&](ll bytes) { char* r = p; p += (bytes + 255) & ~255LL; return r; };
  __bf16* Adown  = (__bf16*)alloc(147456LL * 2);
  __bf16* Ai2h   = (__bf16*)alloc(110592LL * 2);
  __bf16* Afi    = (__bf16*)alloc(51200LL * 2);
  __bf16* Afh    = (__bf16*)alloc(51200LL * 2);
  __bf16* Afl    = (__bf16*)alloc(12800LL * 2);
  __bf16* Aret   = (__bf16*)alloc(61440LL * 2);
  __bf16* seq    = (__bf16*)alloc((ll)NT * NB * 4096 * 64 * 2);
  __bf16* f1buf  = (__bf16*)alloc((ll)NB * 4096 * 32 * 2);
  __bf16* hzb    = (__bf16*)alloc(H_N * 2);
  __bf16* hbufA  = (__bf16*)alloc(H_N * 2);
  __bf16* hbufB  = (__bf16*)alloc(H_N * 2);
  __bf16* i2h_sl = (__bf16*)alloc(slabT * I2H_T * 2);
  __bf16* i2f_sl = (__bf16*)alloc(slabT * I2F_T * 2);
  if (p > (char*)d_ws + ws_size) return;

  hipMemsetAsync(hzb, 0, (size_t)H_N * 2, stream);

  k_prep<<<1698, 256, 0, stream>>>(W_down, W_i2h, W_i2f, W_h2f, W_flow, W_ret,
                                   Adown, Ai2h, Afi, Afh, Afl, Aret);
  k_down<<<NB * 64 * 4, 256, 0, stream>>>(x, Adown, b_down, seq);

  if (fits) {
    k_i2h2<<<NT * NB * 32, 256, 0, stream>>>(seq, Ai2h, b_i2h, i2h_sl);
    k_conv5<false, 4><<<NT * NB * 16, 256, 0, stream>>>(seq, Afi, nullptr,
                                                        nullptr, nullptr, i2f_sl);
  }

  const ll osb = (ll)NT * NF * HWSZ;
  for (int t = 0; t < NT; ++t) {
    const __bf16* xt0 = seq + (ll)t * NB * 4096 * 64;
    if (!fits) {
      k_i2h2<<<NB * 32, 256, 0, stream>>>(xt0, Ai2h, b_i2h, i2h_sl);
      k_conv5<false, 4><<<NB * 16, 256, 0, stream>>>(xt0, Afi, nullptr,
                                                     nullptr, nullptr, i2f_sl);
    }
    int ti = fits ? t : 0;
    const __bf16* hb = (t == 0) ? hzb : ((t & 1) ? hbufA : hbufB);
    __bf16* hbc = (t & 1) ? hbufB : hbufA;
    const float* hpf = (t == 0) ? out : out + (ll)(t - 1) * NF * HWSZ;

    k_conv5<true, 2><<<NB * 32, 256, 0, stream>>>(hb, Afh, b_i2f, b_h2f,
                                                  i2f_sl + (ll)ti * I2F_T, f1buf);
    k_fwr<<<NB * 64, 256, 0, stream>>>(f1buf, Afl, b_flow, hb, Aret, b_ret,
                                       i2h_sl + (ll)ti * I2H_T, hpf,
                                       (t == 0) ? 1 : 0,
                                       out + (ll)t * NF * HWSZ, osb, hbc);
  }
}